// Round 3
// baseline (3062.291 us; speedup 1.0000x reference)
//
#include <hip/hip_runtime.h>
#include <stdint.h>

#define NM 128   // matrix dim / electrons
#define NT 512   // 8 waves; thread t: h = t>>7 (column chunk), r = t&127 (row)

// Full-wave (64-lane) unsigned max via DPP (VALU pipe, ~60cy chain).
// Result valid in lane 63. Standard GCN/CDNA sequence; bound_ctrl=true
// fills invalid lanes with 0 (identity for unsigned max).
__device__ __forceinline__ unsigned wave_max_dpp(unsigned x) {
    int v = (int)x;
#define DPP_STEP(ctrl) \
    { int o = __builtin_amdgcn_update_dpp(0, v, ctrl, 0xf, 0xf, true); \
      v = ((unsigned)o > (unsigned)v) ? o : v; }
    DPP_STEP(0x111)  // row_shr:1
    DPP_STEP(0x112)  // row_shr:2
    DPP_STEP(0x114)  // row_shr:4
    DPP_STEP(0x118)  // row_shr:8
    DPP_STEP(0x142)  // row_bcast:15
    DPP_STEP(0x143)  // row_bcast:31
#undef DPP_STEP
    return (unsigned)v;
}

__device__ __forceinline__ unsigned pack_key(float v, int r) {
    // monotone in |v|; drops 6 mantissa LSBs to make room for the row id
    return (((__float_as_uint(v) & 0x7fffffffu) >> 6) << 7) | (unsigned)r;
}

__global__ __launch_bounds__(NT, 4)
void slater_logdet(const float* __restrict__ rs,
                   const float* __restrict__ kpts,
                   const float* __restrict__ csw,
                   const float* __restrict__ ssw,
                   float* __restrict__ out) {
    __shared__ __align__(16) float prow[NM];   // published pivot row
    __shared__ float colv[2][NM];              // column-k values, double-buffered
    __shared__ unsigned red2[2 * NM];          // per-wave argmax keys, per step

    const int t  = threadIdx.x;
    const int b  = blockIdx.x;
    const int h  = t >> 7;
    const int r  = t & 127;
    const int c0 = h << 5;
    const int wid = (t >> 6) & 1;  // wave id within the h-group

    const float x = rs[(b * NM + r) * 3 + 0];
    const float y = rs[(b * NM + r) * 3 + 1];
    const float z = rs[(b * NM + r) * 3 + 2];

    // fill: s[j] = cs[m]*cos(k_m.r) - ss[m]*sin(k_m.r),  m = c0 + j
    float s[32];
#pragma unroll
    for (int j = 0; j < 32; ++j) {
        const int m = c0 + j;
        const float d = kpts[m * 3 + 0] * x + kpts[m * 3 + 1] * y + kpts[m * 3 + 2] * z;
        float sn, cn;
        __sincosf(d, &sn, &cn);
        s[j] = csw[m] * cn - ssw[m] * sn;
    }

    bool  elim = false;
    float acc  = 0.0f;

    // bootstrap: publish column 0 + its argmax keys
    if (h == 0) {
        colv[0][r] = s[0];
        const unsigned wmax = wave_max_dpp(pack_key(s[0], r));
        if ((t & 63) == 63) red2[wid] = wmax;
    }
    __syncthreads();

    for (int k = 0; k < NM; ++k) {
        // ---- pivot id from pre-reduced keys (one LDS uint2 read) ----
        const uint2 kk = *(const uint2*)&red2[2 * k];
        const int p = (int)((kk.x > kk.y ? kk.x : kk.y) & 127u);
        const bool isp = (r == p);

        if (isp && c0 + 31 >= k) {   // pivot row publishes its live chunks
            float4* pr4 = (float4*)&prow[c0];
#pragma unroll
            for (int j4 = 0; j4 < 8; ++j4)
                pr4[j4] = make_float4(s[4 * j4 + 0], s[4 * j4 + 1],
                                      s[4 * j4 + 2], s[4 * j4 + 3]);
        }
        if (isp) elim = true;
        __syncthreads();  // A: prow visible

        const float piv = prow[k];
        if (t == 0) acc += __logf(fabsf(piv));

        if (k < NM - 1 && c0 + 31 >= k) {
            // ---- rank-1 update in registers ----
            const float l = elim ? 0.0f
                : colv[k & 1][r] * __builtin_amdgcn_rcpf(piv);
            const float4* pr4 = (const float4*)&prow[c0];
#pragma unroll
            for (int j4 = 0; j4 < 8; ++j4) {
                const float4 u = pr4[j4];
                s[4 * j4 + 0] -= l * u.x;
                s[4 * j4 + 1] -= l * u.y;
                s[4 * j4 + 2] -= l * u.z;
                s[4 * j4 + 3] -= l * u.w;
            }
            // ---- pipelined next-column publish + argmax (owning group) ----
            if (h == ((k + 1) >> 5)) {
                const int jt = (k + 1) & 31;
                float a[16];
#pragma unroll
                for (int i = 0; i < 16; ++i) a[i] = (jt & 1) ? s[2 * i + 1] : s[2 * i];
#pragma unroll
                for (int i = 0; i < 8; ++i)  a[i] = (jt & 2) ? a[2 * i + 1] : a[2 * i];
#pragma unroll
                for (int i = 0; i < 4; ++i)  a[i] = (jt & 4) ? a[2 * i + 1] : a[2 * i];
#pragma unroll
                for (int i = 0; i < 2; ++i)  a[i] = (jt & 8) ? a[2 * i + 1] : a[2 * i];
                const float cand = (jt & 16) ? a[1] : a[0];

                colv[(k + 1) & 1][r] = cand;
                const unsigned key = elim ? 0u : pack_key(cand, r);
                const unsigned wmax = wave_max_dpp(key);
                if ((t & 63) == 63) red2[2 * (k + 1) + wid] = wmax;
            }
        }
        __syncthreads();  // B: red2/colv for step k+1 visible
    }

    if (t == 0) out[b] = acc;
}

extern "C" void kernel_launch(void* const* d_in, const int* in_sizes, int n_in,
                              void* d_out, int out_size, void* d_ws, size_t ws_size,
                              hipStream_t stream) {
    const float* rs = (const float*)d_in[0];
    const float* kp = (const float*)d_in[1];
    const float* cs = (const float*)d_in[2];
    const float* ss = (const float*)d_in[3];
    float* out = (float*)d_out;
    const int batch = in_sizes[0] / (NM * 3);  // 4096
    slater_logdet<<<dim3(batch), dim3(NT), 0, stream>>>(rs, kp, cs, ss, out);
}

// Round 4
// 821.174 us; speedup vs baseline: 3.7292x; 3.7292x over previous
//
#include <hip/hip_runtime.h>
#include <stdint.h>

#define NM 128   // matrix dim / electrons
#define NT 512   // 8 waves; wave w owns cols [16w..16w+15]; lane l owns rows l, l+64

__device__ __forceinline__ float readlane_f(float v, int lane) {
    return __int_as_float(__builtin_amdgcn_readlane(__float_as_int(v), lane));
}

// Full 64-lane unsigned max via DPP (VALU pipe); result valid in lane 63.
__device__ __forceinline__ unsigned wave_max_dpp(unsigned x) {
    int v = (int)x;
#define DPP_STEP(ctrl) \
    { int o = __builtin_amdgcn_update_dpp(0, v, ctrl, 0xf, 0xf, true); \
      v = ((unsigned)o > (unsigned)v) ? o : v; }
    DPP_STEP(0x111)  // row_shr:1
    DPP_STEP(0x112)  // row_shr:2
    DPP_STEP(0x114)  // row_shr:4
    DPP_STEP(0x118)  // row_shr:8
    DPP_STEP(0x142)  // row_bcast:15
    DPP_STEP(0x143)  // row_bcast:31
#undef DPP_STEP
    return (unsigned)v;
}

__device__ __forceinline__ unsigned pack_key(float v, int r) {
    // monotone in |v|; drop 7 low bits for the row id (ties -> larger row, fine)
    return (((__float_as_uint(v) & 0x7fffffffu) >> 6) << 7) | (unsigned)r;
}

__global__ __launch_bounds__(NT, 4)
void slater_logdet(const float* __restrict__ rs,
                   const float* __restrict__ kpts,
                   const float* __restrict__ csw,
                   const float* __restrict__ ssw,
                   float* __restrict__ out) {
    __shared__ float    colv[2][NM];  // column-k multiplier numerators (dbl-buf)
    __shared__ float    pivv[2];      // exact pivot value (dbl-buf)
    __shared__ unsigned red[NM];      // packed argmax key per step

    const int t  = threadIdx.x;
    const int b  = blockIdx.x;
    const int w  = t >> 6;    // wave id = column-slab id
    const int l  = t & 63;
    const int c0 = w << 4;    // first column of my slab
    const int r0 = l, r1 = l + 64;

    // positions of my two rows
    const float x0 = rs[(b * NM + r0) * 3 + 0];
    const float y0 = rs[(b * NM + r0) * 3 + 1];
    const float z0 = rs[(b * NM + r0) * 3 + 2];
    const float x1 = rs[(b * NM + r1) * 3 + 0];
    const float y1 = rs[(b * NM + r1) * 3 + 1];
    const float z1 = rs[(b * NM + r1) * 3 + 2];

    // fill: s[j] = row r0, col c0+j ; s[j+16] = row r1, col c0+j
    float s[32];
#pragma unroll
    for (int j = 0; j < 16; ++j) {
        const int m = c0 + j;                       // wave-uniform -> scalar loads
        const float kx = kpts[m * 3 + 0], ky = kpts[m * 3 + 1], kz = kpts[m * 3 + 2];
        const float cw = csw[m], sw = ssw[m];
        float sn, cn;
        __sincosf(kx * x0 + ky * y0 + kz * z0, &sn, &cn);
        s[j] = cw * cn - sw * sn;
        __sincosf(kx * x1 + ky * y1 + kz * z1, &sn, &cn);
        s[j + 16] = cw * cn - sw * sn;
    }

    bool  elim0 = false, elim1 = false;
    float acc = 0.0f;

    // bootstrap: wave 0 publishes column 0 (values, argmax key, exact pivot)
    if (w == 0) {
        const float cand0 = s[0], cand1 = s[16];
        colv[0][r0] = cand0;
        colv[0][r1] = cand1;
        const unsigned k0 = pack_key(cand0, r0), k1 = pack_key(cand1, r1);
        unsigned vmax = wave_max_dpp(k0 > k1 ? k0 : k1);
        vmax = (unsigned)__builtin_amdgcn_readlane((int)vmax, 63);
        const int p = (int)(vmax & 127u);
        if (l == (p & 63)) pivv[0] = (p >> 6) ? cand1 : cand0;
        if (l == 63) red[0] = vmax;
    }
    __syncthreads();

    for (int k = 0; k < NM; ++k) {
        const float pv = pivv[k & 1];            // exact pivot (broadcast)
        const int   p  = (int)(red[k] & 127u);   // pivot row id (broadcast)
        if (t == 0) acc += __logf(fabsf(pv));

        elim0 |= (r0 == p);
        elim1 |= (r1 == p);

        const int kn = k + 1;
        if (c0 + 15 >= kn) {                     // my slab still has live columns
            // pivot-row slab via readlane (parallel with the LDS reads above)
            const int pu = __builtin_amdgcn_readfirstlane(p);
            float u[16];
            if (pu < 64) {
#pragma unroll
                for (int j = 0; j < 16; ++j) u[j] = readlane_f(s[j], pu);
            } else {
#pragma unroll
                for (int j = 0; j < 16; ++j) u[j] = readlane_f(s[j + 16], pu - 64);
            }

            const float rcpP = __builtin_amdgcn_rcpf(pv);
            const float l0 = elim0 ? 0.0f : colv[k & 1][r0] * rcpP;
            const float l1 = elim1 ? 0.0f : colv[k & 1][r1] * rcpP;

            const bool owner = ((kn >> 4) == w); // wave-uniform
            const int  jn    = kn & 15;
            float cand0 = 0.0f, cand1 = 0.0f;
#pragma unroll
            for (int j = 0; j < 16; ++j) {
                s[j]      -= l0 * u[j];
                s[j + 16] -= l1 * u[j];
                if (owner && (j == jn)) { cand0 = s[j]; cand1 = s[j + 16]; }
            }

            if (owner) {                         // publish step-kn column
                colv[kn & 1][r0] = cand0;
                colv[kn & 1][r1] = cand1;
                const unsigned k0 = elim0 ? 0u : pack_key(cand0, r0);
                const unsigned k1 = elim1 ? 0u : pack_key(cand1, r1);
                unsigned vmax = wave_max_dpp(k0 > k1 ? k0 : k1);
                vmax = (unsigned)__builtin_amdgcn_readlane((int)vmax, 63);
                const int pn = (int)(vmax & 127u);
                if (l == (pn & 63)) pivv[kn & 1] = (pn >> 6) ? cand1 : cand0;
                if (l == 63) red[kn] = vmax;
            }
        }
        __syncthreads();   // the ONLY barrier per step
    }

    if (t == 0) out[b] = acc;
}

extern "C" void kernel_launch(void* const* d_in, const int* in_sizes, int n_in,
                              void* d_out, int out_size, void* d_ws, size_t ws_size,
                              hipStream_t stream) {
    const float* rs = (const float*)d_in[0];
    const float* kp = (const float*)d_in[1];
    const float* cs = (const float*)d_in[2];
    const float* ss = (const float*)d_in[3];
    float* out = (float*)d_out;
    const int batch = in_sizes[0] / (NM * 3);  // 4096
    slater_logdet<<<dim3(batch), dim3(NT), 0, stream>>>(rs, kp, cs, ss, out);
}

// Round 5
// 715.589 us; speedup vs baseline: 4.2794x; 1.1475x over previous
//
#include <hip/hip_runtime.h>
#include <stdint.h>

#define NM 128   // matrix dim / electrons
#define NT 512   // 8 waves; wave w owns cols [16w..16w+15]; lane l owns rows l, l+64

__device__ __forceinline__ float readlane_f(float v, int lane) {
    return __int_as_float(__builtin_amdgcn_readlane(__float_as_int(v), lane));
}

// Full 64-lane unsigned max via DPP (VALU pipe); result valid in lane 63.
__device__ __forceinline__ unsigned wave_max_dpp(unsigned x) {
    int v = (int)x;
#define DPP_STEP(ctrl) \
    { int o = __builtin_amdgcn_update_dpp(0, v, ctrl, 0xf, 0xf, true); \
      v = ((unsigned)o > (unsigned)v) ? o : v; }
    DPP_STEP(0x111)  // row_shr:1
    DPP_STEP(0x112)  // row_shr:2
    DPP_STEP(0x114)  // row_shr:4
    DPP_STEP(0x118)  // row_shr:8
    DPP_STEP(0x142)  // row_bcast:15
    DPP_STEP(0x143)  // row_bcast:31
#undef DPP_STEP
    return (unsigned)v;
}

__device__ __forceinline__ unsigned pack_key(float v, int r) {
    // monotone in |v|; drop 6 mantissa LSBs to make room for the 7-bit row id
    return (((__float_as_uint(v) & 0x7fffffffu) >> 6) << 7) | (unsigned)r;
}

// max(ka,kb) over the wave, broadcast to all lanes (uniform result)
__device__ __forceinline__ unsigned argmax_bcast(unsigned ka, unsigned kb) {
    const unsigned m = wave_max_dpp(ka > kb ? ka : kb);
    return (unsigned)__builtin_amdgcn_readlane((int)m, 63);
}

// select s[B + 2*jb] for uniform jb in [0,8): 7 cndmasks, no dynamic indexing
template<int B>
__device__ __forceinline__ float sel8(const float (&s)[32], int jb) {
    const float a0 = (jb & 1) ? s[B + 2]  : s[B + 0];
    const float a1 = (jb & 1) ? s[B + 6]  : s[B + 4];
    const float a2 = (jb & 1) ? s[B + 10] : s[B + 8];
    const float a3 = (jb & 1) ? s[B + 14] : s[B + 12];
    const float b0 = (jb & 2) ? a1 : a0;
    const float b1 = (jb & 2) ? a3 : a2;
    return (jb & 4) ? b1 : b0;
}

// fused rank-2 update of a 16-column slab; P0LO/P1LO = pivot row in low half
template<bool P0LO, bool P1LO>
__device__ __forceinline__ void update16(float (&s)[32], int p0l, int p1l,
                                         float lp1, float l0a, float l0b,
                                         float l1a, float l1b) {
#pragma unroll
    for (int j = 0; j < 16; ++j) {
        const float u0 = P0LO ? readlane_f(s[j], p0l) : readlane_f(s[j + 16], p0l);
        const float t1 = P1LO ? readlane_f(s[j], p1l) : readlane_f(s[j + 16], p1l);
        const float u1 = t1 - lp1 * u0;     // row p1 post-step-k
        s[j]      -= l0a * u0 + l1a * u1;
        s[j + 16] -= l0b * u0 + l1b * u1;
    }
}

__global__ __launch_bounds__(NT, 4)
void slater_logdet(const float* __restrict__ rs,
                   const float* __restrict__ kpts,
                   const float* __restrict__ csw,
                   const float* __restrict__ ssw,
                   float* __restrict__ out) {
    // pub[i] = {piv_{2i}, piv_{2i+1}, key_{2i}, key_{2i+1}} — write-once per slot
    __shared__ __align__(16) float4 pub[NM / 2];
    // colv[parity][r] = {col 2i value post-(2i-1), col 2i+1 value post-2i}
    __shared__ float2 colv[2][NM];
    __shared__ float redf[NT / 64];

    const int t  = threadIdx.x;
    const int b  = blockIdx.x;
    const int w  = t >> 6;    // wave id = column-slab id
    const int l  = t & 63;
    const int c0 = w << 4;
    const int r0 = l, r1 = l + 64;

    const float x0 = rs[(b * NM + r0) * 3 + 0];
    const float y0 = rs[(b * NM + r0) * 3 + 1];
    const float z0 = rs[(b * NM + r0) * 3 + 2];
    const float x1 = rs[(b * NM + r1) * 3 + 0];
    const float y1 = rs[(b * NM + r1) * 3 + 1];
    const float z1 = rs[(b * NM + r1) * 3 + 2];

    float s[32];   // s[j] = row r0 col c0+j ; s[j+16] = row r1 col c0+j
#pragma unroll
    for (int j = 0; j < 16; ++j) {
        const int m = c0 + j;  // wave-uniform -> scalar loads
        const float kx = kpts[m * 3 + 0], ky = kpts[m * 3 + 1], kz = kpts[m * 3 + 2];
        const float cw = csw[m], sw = ssw[m];
        float sn, cn;
        __sincosf(kx * x0 + ky * y0 + kz * z0, &sn, &cn);
        s[j] = cw * cn - sw * sn;
        __sincosf(kx * x1 + ky * y1 + kz * z1, &sn, &cn);
        s[j + 16] = cw * cn - sw * sn;
    }

    bool elim0 = false, elim1 = false;

    // ---- bootstrap: wave 0 publishes steps 0 and 1 ----
    if (w == 0) {
        const float c0a = s[0], c0b = s[16];
        const float c1p = s[1], c1q = s[17];
        const unsigned key0 = argmax_bcast(pack_key(c0a, r0), pack_key(c0b, r1));
        const int p0 = (int)(key0 & 127u);
        const float piv0 = (p0 < 64) ? readlane_f(c0a, p0) : readlane_f(c0b, p0 - 64);
        const float u01  = (p0 < 64) ? readlane_f(c1p, p0) : readlane_f(c1q, p0 - 64);
        const float rcp0 = __builtin_amdgcn_rcpf(piv0);
        const bool e0 = (r0 == p0), e1 = (r1 == p0);
        const float l0a = e0 ? 0.0f : c0a * rcp0;
        const float l0b = e1 ? 0.0f : c0b * rcp0;
        const float c1a = c1p - l0a * u01;
        const float c1b = c1q - l0b * u01;
        const unsigned key1 = argmax_bcast(e0 ? 0u : pack_key(c1a, r0),
                                           e1 ? 0u : pack_key(c1b, r1));
        const int p1 = (int)(key1 & 127u);
        const float piv1 = (p1 < 64) ? readlane_f(c1a, p1) : readlane_f(c1b, p1 - 64);
        colv[0][r0] = make_float2(c0a, c1a);
        colv[0][r1] = make_float2(c0b, c1b);
        if (l == 0) pub[0] = make_float4(piv0, piv1,
                                         __uint_as_float(key0), __uint_as_float(key1));
    }
    __syncthreads();

    // ---- main loop: one barrier per 2 elimination steps ----
    for (int k = 0; k < NM - 2; k += 2) {
        if (c0 + 15 >= k + 2) {          // live slab; dead waves only barrier
            const int rd = k >> 1;
            const float4 pb = pub[rd];
            const unsigned key0 = __float_as_uint(pb.z);
            const unsigned key1 = __float_as_uint(pb.w);
            const int p0 = (int)(key0 & 127u), p1 = (int)(key1 & 127u);
            const float rcp0 = __builtin_amdgcn_rcpf(pb.x);
            const float rcp1 = __builtin_amdgcn_rcpf(pb.y);
            const float2 ca = colv[rd & 1][r0];
            const float2 cb = colv[rd & 1][r1];
            elim0 |= (r0 == p0); elim1 |= (r1 == p0);
            const float l0a = elim0 ? 0.0f : ca.x * rcp0;
            const float l0b = elim1 ? 0.0f : cb.x * rcp0;
            elim0 |= (r0 == p1); elim1 |= (r1 == p1);
            const float l1a = elim0 ? 0.0f : ca.y * rcp1;
            const float l1b = elim1 ? 0.0f : cb.y * rcp1;
            const float lp1 = colv[rd & 1][p1].x * rcp0;   // broadcast read

            const int p0u = __builtin_amdgcn_readfirstlane(p0);
            const int p1u = __builtin_amdgcn_readfirstlane(p1);
            if (p0u < 64) {
                if (p1u < 64) update16<true, true >(s, p0u,      p1u,      lp1, l0a, l0b, l1a, l1b);
                else          update16<true, false>(s, p0u,      p1u - 64, lp1, l0a, l0b, l1a, l1b);
            } else {
                if (p1u < 64) update16<false, true >(s, p0u - 64, p1u,      lp1, l0a, l0b, l1a, l1b);
                else          update16<false, false>(s, p0u - 64, p1u - 64, lp1, l0a, l0b, l1a, l1b);
            }

            // ---- look-ahead publish of steps k+2, k+3 (single owner wave) ----
            if (w == ((k + 2) >> 4)) {
                const int jb = ((k + 2) & 15) >> 1;        // uniform, even col pair
                const float c2a = sel8<0 >(s, jb), c2b = sel8<16>(s, jb);
                const float c3p = sel8<1 >(s, jb), c3q = sel8<17>(s, jb);
                const unsigned key2 = argmax_bcast(elim0 ? 0u : pack_key(c2a, r0),
                                                   elim1 ? 0u : pack_key(c2b, r1));
                const int p2 = (int)(key2 & 127u);
                const float piv2 = (p2 < 64) ? readlane_f(c2a, p2) : readlane_f(c2b, p2 - 64);
                const float u23  = (p2 < 64) ? readlane_f(c3p, p2) : readlane_f(c3q, p2 - 64);
                const float rcp2 = __builtin_amdgcn_rcpf(piv2);
                const bool e0 = elim0 || (r0 == p2), e1 = elim1 || (r1 == p2);
                const float l2a = e0 ? 0.0f : c2a * rcp2;
                const float l2b = e1 ? 0.0f : c2b * rcp2;
                const float c3a = c3p - l2a * u23;
                const float c3b = c3q - l2b * u23;
                const unsigned key3 = argmax_bcast(e0 ? 0u : pack_key(c3a, r0),
                                                   e1 ? 0u : pack_key(c3b, r1));
                const int p3 = (int)(key3 & 127u);
                const float piv3 = (p3 < 64) ? readlane_f(c3a, p3) : readlane_f(c3b, p3 - 64);
                colv[(rd + 1) & 1][r0] = make_float2(c2a, c3a);
                colv[(rd + 1) & 1][r1] = make_float2(c2b, c3b);
                if (l == 0) pub[rd + 1] = make_float4(piv2, piv3,
                                 __uint_as_float(key2), __uint_as_float(key3));
            }
        }
        __syncthreads();
    }

    // ---- log|det| = sum log|piv_k| over the write-once pub array ----
    float lg = 0.0f;
    if (t < NM) {
        const float4 pb = pub[t >> 1];
        const float pv = (t & 1) ? pb.y : pb.x;
        lg = __logf(fabsf(pv));
    }
#pragma unroll
    for (int off = 32; off > 0; off >>= 1)
        lg += __shfl_xor(lg, off, 64);
    if ((t & 63) == 0) redf[t >> 6] = lg;
    __syncthreads();
    if (t == 0) out[b] = redf[0] + redf[1];
}

extern "C" void kernel_launch(void* const* d_in, const int* in_sizes, int n_in,
                              void* d_out, int out_size, void* d_ws, size_t ws_size,
                              hipStream_t stream) {
    const float* rs = (const float*)d_in[0];
    const float* kp = (const float*)d_in[1];
    const float* cs = (const float*)d_in[2];
    const float* ss = (const float*)d_in[3];
    float* out = (float*)d_out;
    const int batch = in_sizes[0] / (NM * 3);  // 4096
    slater_logdet<<<dim3(batch), dim3(NT), 0, stream>>>(rs, kp, cs, ss, out);
}